// Round 5
// baseline (191.197 us; speedup 1.0000x reference)
//
#include <hip/hip_runtime.h>
#include <hip/hip_bf16.h>
#include <cstdint>
#include <cstddef>

// Problem constants
#define B_ 8
#define N_ 2048
#define D_ 256
#define H_ 8
#define HD_ 32
#define LN_EPS 1e-5f
#define QSCALE 0.25506275f  // log2(e)/sqrt(32): folded into Q so p = exp2(q'.k)

typedef __attribute__((ext_vector_type(8))) short short8;
typedef __attribute__((ext_vector_type(4))) float f32x4;
typedef __attribute__((ext_vector_type(16))) float f32x16;

static __device__ __forceinline__ float exp2v(float x) {
#if __has_builtin(__builtin_amdgcn_exp2f)
    return __builtin_amdgcn_exp2f(x);
#else
    float r;
    asm("v_exp_f32 %0, %1" : "=v"(r) : "v"(x));
    return r;
#endif
}

static __device__ __forceinline__ unsigned short f2bf(float f) {
    union { float f; unsigned int u; } v; v.f = f;
    unsigned int r = v.u + 0x7fffu + ((v.u >> 16) & 1u);
    return (unsigned short)(r >> 16);
}

static __device__ __forceinline__ unsigned int cvtpk(float lo, float hi) {
    unsigned int d;
    asm("v_cvt_pk_bf16_f32 %0, %1, %2" : "=v"(d) : "v"(lo), "v"(hi));
    return d;
}

// ---------------- prep: x fp32 -> bf16 ----------------
__global__ __launch_bounds__(256) void k_prep_x(const float* __restrict__ x,
                                                unsigned short* __restrict__ xbf, int n4) {
    int i = blockIdx.x * 256 + threadIdx.x;
    if (i >= n4) return;
    float4 v = reinterpret_cast<const float4*>(x)[i];
    ushort4 o;
    o.x = f2bf(v.x); o.y = f2bf(v.y); o.z = f2bf(v.z); o.w = f2bf(v.w);
    reinterpret_cast<ushort4*>(xbf)[i] = o;
}

// ---------------- prep: W fp32 -> bf16 transposed wt[mat][col][k] ----------------
__global__ __launch_bounds__(256) void k_prep_w(const float* __restrict__ w0, const float* __restrict__ w1,
                                                const float* __restrict__ w2, const float* __restrict__ w3,
                                                unsigned short* __restrict__ wt) {
    int c = blockIdx.x, mat = blockIdx.y, k = threadIdx.x;
    const float* w = (mat == 0) ? w0 : (mat == 1) ? w1 : (mat == 2) ? w2 : w3;
    wt[((size_t)(mat * 256 + c)) * 256 + k] = f2bf(w[k * 256 + c]);
}

// ---------------- adjacency -> bitmask (streaming, int4 + shfl-OR pack) ----------------
__global__ __launch_bounds__(256) void k_mask(const int* __restrict__ adj,
                                              unsigned int* __restrict__ mbg) {
    int wave = (blockIdx.x * 256 + threadIdx.x) >> 6;   // 0..8191
    int lane = threadIdx.x & 63;
    int shamt = 4 * (lane & 7);
    int g8 = lane >> 3;
    const int4* p = reinterpret_cast<const int4*>(adj) + (size_t)wave * 1024 + lane;
    unsigned int* outp = mbg + (size_t)wave * 128;
#pragma unroll
    for (int i = 0; i < 16; ++i) {
        int4 v = p[i * 64];
        unsigned int nib = (v.x != 0 ? 1u : 0u) | (v.y != 0 ? 2u : 0u)
                         | (v.z != 0 ? 4u : 0u) | (v.w != 0 ? 8u : 0u);
        unsigned int r = nib << shamt;
        r |= (unsigned int)__shfl_xor((int)r, 1, 64);
        r |= (unsigned int)__shfl_xor((int)r, 2, 64);
        r |= (unsigned int)__shfl_xor((int)r, 4, 64);
        if ((lane & 7) == 0) outp[i * 8 + g8] = r;
    }
}

// ---------------- fused QKV projection GEMM ----------------
__global__ __launch_bounds__(256) void k_qkv(const unsigned short* __restrict__ xbf,
                                             const unsigned short* __restrict__ wt,
                                             const float* __restrict__ bq, const float* __restrict__ bk,
                                             const float* __restrict__ bv,
                                             unsigned short* __restrict__ Qb, unsigned short* __restrict__ Kb,
                                             unsigned short* __restrict__ Vs) {
    int mat = blockIdx.y;
    int lane = threadIdx.x & 63;
    int wv = threadIdx.x >> 6;
    int row0 = blockIdx.x * 64 + wv * 16;
    int l15 = lane & 15, lg = lane >> 4;
    const float* bias = (mat == 0) ? bq : (mat == 1) ? bk : bv;
    const float qs = (mat == 0) ? QSCALE : 1.0f;
    const unsigned short* wm = wt + (size_t)mat * 65536;

    short8 af[8];
    const unsigned short* xrow = xbf + (size_t)(row0 + l15) * 256 + lg * 8;
#pragma unroll
    for (int kk = 0; kk < 8; ++kk)
        af[kk] = *reinterpret_cast<const short8*>(xrow + kk * 32);

    int b = row0 >> 11;            // 2048 rows per batch; 64-row blocks never cross
    int nbase = (row0 & 2047) + lg * 4;

    for (int ci = 0; ci < 16; ++ci) {
        const unsigned short* wrow = wm + (size_t)(ci * 16 + l15) * 256 + lg * 8;
        f32x4 acc = {0.f, 0.f, 0.f, 0.f};
#pragma unroll
        for (int kk = 0; kk < 8; ++kk) {
            short8 bfg = *reinterpret_cast<const short8*>(wrow + kk * 32);
            acc = __builtin_amdgcn_mfma_f32_16x16x32_bf16(af[kk], bfg, acc, 0, 0, 0);
        }
        int col = ci * 16 + l15;
        float bcol = bias[col];
        int h = col >> 5, hd = col & 31;
        if (mat < 2) {
            unsigned short* dst = (mat == 0) ? Qb : Kb;
#pragma unroll
            for (int r = 0; r < 4; ++r) {
                size_t off = ((size_t)(b * 8 + h) * 2048 + nbase + r) * 32 + hd;
                dst[off] = f2bf((acc[r] + bcol) * qs);
            }
        } else {
            // V fragment-tile layout
            size_t off = (size_t)(b * 8 + h) * 65536
                       + ((size_t)(nbase >> 4) * 32 + hd) * 16 + (nbase & 15);
            ushort4 o;
            o.x = f2bf(acc[0] + bcol); o.y = f2bf(acc[1] + bcol);
            o.z = f2bf(acc[2] + bcol); o.w = f2bf(acc[3] + bcol);
            *reinterpret_cast<ushort4*>(Vs + off) = o;
        }
    }
}

// ---------------- masked attention ----------------
// 1-D grid of 512: b = blk&7 (XCD-affine), q0 = (blk>>3)*32. 8 waves, wave = head.
// Register-prefetched K-loop (load t+1 at top, compute held t): hides L2 latency.
// S^T = mfma(K, Q); p = bit ? exp2(s) : 0; P packed via cvt_pk + permlane32_swap;
// att^T += mfma(V_tile, P).
__global__ __launch_bounds__(512, 4) void k_attn(const unsigned short* __restrict__ Qb,
                                                 const unsigned short* __restrict__ Kb,
                                                 const unsigned short* __restrict__ Vs,
                                                 const unsigned int* __restrict__ mbg,
                                                 unsigned short* __restrict__ att) {
    __shared__ unsigned int mbits[32][66];   // +2 pad: 2-way max conflict (free)
    int tid = threadIdx.x;
    int lane = tid & 63, hw = tid >> 6;
    int l31 = lane & 31, hi = lane >> 5;
    int b = blockIdx.x & 7;
    int q0 = (blockIdx.x >> 3) * 32;

    // ---- load this block's 8KB bitmask (one int4 per thread) ----
    {
        int row = tid >> 4, c0 = (tid & 15) * 4;
        uint4 v4 = *reinterpret_cast<const uint4*>(mbg + ((size_t)(b * N_ + q0 + row)) * 64 + c0);
        mbits[row][c0] = v4.x; mbits[row][c0 + 1] = v4.y;
        mbits[row][c0 + 2] = v4.z; mbits[row][c0 + 3] = v4.w;
    }
    __syncthreads();

    int bh = b * 8 + hw;
    const unsigned short* Qh = Qb + (size_t)bh * N_ * HD_;
    const unsigned short* Kh = Kb + (size_t)bh * N_ * HD_;
    const unsigned short* Vh = Vs + (size_t)bh * 65536;

    short8 qf0 = *reinterpret_cast<const short8*>(Qh + (size_t)(q0 + l31) * HD_ + hi * 8);
    short8 qf1 = *reinterpret_cast<const short8*>(Qh + (size_t)(q0 + l31) * HD_ + hi * 8 + 16);
    const unsigned short* krow = Kh + (size_t)l31 * HD_ + hi * 8;
    const unsigned short* vfp = Vh + (size_t)l31 * 16 + hi * 8;   // + tile*512

    const f32x16 fz = {0.f,0.f,0.f,0.f,0.f,0.f,0.f,0.f,0.f,0.f,0.f,0.f,0.f,0.f,0.f,0.f};
    f32x16 attacc = fz;
    float lsum = 0.f;
    const unsigned int* mrow = &mbits[l31][0];

    // prologue: load iteration 0
    short8 kc0 = *reinterpret_cast<const short8*>(krow);
    short8 kc1 = *reinterpret_cast<const short8*>(krow + 16);
    short8 vc0 = *reinterpret_cast<const short8*>(vfp);
    short8 vc1 = *reinterpret_cast<const short8*>(vfp + 512);
    unsigned int wc = mrow[0];

#pragma unroll 1
    for (int it = 0; it < 64; ++it) {
        // prefetch next iteration (clamped: last iter re-reads itself, harmless)
        int itn = (it < 63) ? it + 1 : 63;
        short8 kn0 = *reinterpret_cast<const short8*>(krow + (size_t)itn * 1024);
        short8 kn1 = *reinterpret_cast<const short8*>(krow + (size_t)itn * 1024 + 16);
        short8 vn0 = *reinterpret_cast<const short8*>(vfp + (size_t)itn * 1024);
        short8 vn1 = *reinterpret_cast<const short8*>(vfp + (size_t)itn * 1024 + 512);
        unsigned int wn = mrow[itn];

        __builtin_amdgcn_s_setprio(1);
        f32x16 s = __builtin_amdgcn_mfma_f32_32x32x16_bf16(kc0, qf0, fz, 0, 0, 0);
        s = __builtin_amdgcn_mfma_f32_32x32x16_bf16(kc1, qf1, s, 0, 0, 0);
        __builtin_amdgcn_s_setprio(0);

        unsigned int pd[4][2];
#pragma unroll
        for (int g = 0; g < 4; ++g) {
            unsigned int nib = (wc >> (8 * g + 4 * hi)) & 15u;
            float p0 = (nib & 1u) ? exp2v(s[4 * g + 0]) : 0.f;
            float p1 = (nib & 2u) ? exp2v(s[4 * g + 1]) : 0.f;
            float p2 = (nib & 4u) ? exp2v(s[4 * g + 2]) : 0.f;
            float p3 = (nib & 8u) ? exp2v(s[4 * g + 3]) : 0.f;
            lsum += (p0 + p1) + (p2 + p3);
            pd[g][0] = cvtpk(p0, p1);
            pd[g][1] = cvtpk(p2, p3);
        }
        asm("v_permlane32_swap_b32 %0, %1" : "+v"(pd[0][0]), "+v"(pd[1][0]));
        asm("v_permlane32_swap_b32 %0, %1" : "+v"(pd[0][1]), "+v"(pd[1][1]));
        asm("v_permlane32_swap_b32 %0, %1" : "+v"(pd[2][0]), "+v"(pd[3][0]));
        asm("v_permlane32_swap_b32 %0, %1" : "+v"(pd[2][1]), "+v"(pd[3][1]));

        union { short8 s8; unsigned int u[4]; } bf0, bf1;
        bf0.u[0] = pd[0][0]; bf0.u[1] = pd[0][1]; bf0.u[2] = pd[1][0]; bf0.u[3] = pd[1][1];
        bf1.u[0] = pd[2][0]; bf1.u[1] = pd[2][1]; bf1.u[2] = pd[3][0]; bf1.u[3] = pd[3][1];

        __builtin_amdgcn_s_setprio(1);
        attacc = __builtin_amdgcn_mfma_f32_32x32x16_bf16(vc0, bf0.s8, attacc, 0, 0, 0);
        attacc = __builtin_amdgcn_mfma_f32_32x32x16_bf16(vc1, bf1.s8, attacc, 0, 0, 0);
        __builtin_amdgcn_s_setprio(0);

        kc0 = kn0; kc1 = kn1; vc0 = vn0; vc1 = vn1; wc = wn;
    }

    float lpart = __shfl_xor(lsum, 32, 64);
    float rcp = 1.f / (lsum + lpart);

    unsigned short* arow = att + ((size_t)b * N_ + q0 + l31) * D_ + hw * HD_;
#pragma unroll
    for (int g = 0; g < 4; ++g) {
        ushort4 o;
        o.x = f2bf(attacc[4 * g + 0] * rcp);
        o.y = f2bf(attacc[4 * g + 1] * rcp);
        o.z = f2bf(attacc[4 * g + 2] * rcp);
        o.w = f2bf(attacc[4 * g + 3] * rcp);
        *reinterpret_cast<ushort4*>(arow + 8 * g + 4 * hi) = o;
    }
}

// ---------------- out projection + residual + LayerNorm ----------------
__global__ __launch_bounds__(256) void k_outln(const unsigned short* __restrict__ att,
                                               const unsigned short* __restrict__ wot,
                                               const float* __restrict__ bo, const float* __restrict__ x,
                                               const float* __restrict__ gamma, const float* __restrict__ beta,
                                               float* __restrict__ out) {
    int lane = threadIdx.x & 63, wv = threadIdx.x >> 6;
    int l15 = lane & 15, lg = lane >> 4;
    int row0 = blockIdx.x * 64 + wv * 16;

    short8 af[8];
    const unsigned short* arow = att + (size_t)(row0 + l15) * 256 + lg * 8;
#pragma unroll
    for (int kk = 0; kk < 8; ++kk)
        af[kk] = *reinterpret_cast<const short8*>(arow + kk * 32);

    float v[16][4];
#pragma unroll
    for (int ci = 0; ci < 16; ++ci) {
        const unsigned short* wrow = wot + (size_t)(ci * 16 + l15) * 256 + lg * 8;
        f32x4 acc = {0.f, 0.f, 0.f, 0.f};
#pragma unroll
        for (int kk = 0; kk < 8; ++kk) {
            short8 bfg = *reinterpret_cast<const short8*>(wrow + kk * 32);
            acc = __builtin_amdgcn_mfma_f32_16x16x32_bf16(af[kk], bfg, acc, 0, 0, 0);
        }
        float bcol = bo[ci * 16 + l15];
#pragma unroll
        for (int r = 0; r < 4; ++r)
            v[ci][r] = acc[r] + bcol + x[(size_t)(row0 + lg * 4 + r) * 256 + ci * 16 + l15];
    }

    float sum[4] = {0.f, 0.f, 0.f, 0.f}, sq[4] = {0.f, 0.f, 0.f, 0.f};
#pragma unroll
    for (int ci = 0; ci < 16; ++ci)
#pragma unroll
        for (int r = 0; r < 4; ++r) {
            sum[r] += v[ci][r];
            sq[r] += v[ci][r] * v[ci][r];
        }
#pragma unroll
    for (int d = 1; d < 16; d <<= 1)
#pragma unroll
        for (int r = 0; r < 4; ++r) {
            sum[r] += __shfl_xor(sum[r], d, 64);
            sq[r] += __shfl_xor(sq[r], d, 64);
        }

    float mu[4], rs[4];
#pragma unroll
    for (int r = 0; r < 4; ++r) {
        mu[r] = sum[r] * (1.f / 256.f);
        float var = sq[r] * (1.f / 256.f) - mu[r] * mu[r];
        rs[r] = rsqrtf(var + LN_EPS);
    }

#pragma unroll
    for (int ci = 0; ci < 16; ++ci) {
        float g = gamma[ci * 16 + l15], be = beta[ci * 16 + l15];
#pragma unroll
        for (int r = 0; r < 4; ++r)
            out[(size_t)(row0 + lg * 4 + r) * 256 + ci * 16 + l15] = (v[ci][r] - mu[r]) * rs[r] * g + be;
    }
}

extern "C" void kernel_launch(void* const* d_in, const int* in_sizes, int n_in,
                              void* d_out, int out_size, void* d_ws, size_t ws_size,
                              hipStream_t stream) {
    (void)in_sizes; (void)n_in; (void)out_size; (void)ws_size;
    const float* x     = (const float*)d_in[0];
    const int*   adj   = (const int*)d_in[1];
    const float* Wq    = (const float*)d_in[2];
    const float* bq    = (const float*)d_in[3];
    const float* Wk    = (const float*)d_in[4];
    const float* bk    = (const float*)d_in[5];
    const float* Wv    = (const float*)d_in[6];
    const float* bv    = (const float*)d_in[7];
    const float* Wo    = (const float*)d_in[8];
    const float* bo    = (const float*)d_in[9];
    const float* gamma = (const float*)d_in[10];
    const float* beta  = (const float*)d_in[11];
    float* out = (float*)d_out;

    char* ws = (char*)d_ws;
    unsigned short* xbf = (unsigned short*)ws; ws += (size_t)16384 * 256 * 2;   // 8.4 MB
    unsigned short* wt  = (unsigned short*)ws; ws += (size_t)4 * 256 * 256 * 2; // 0.5 MB (q,k,v,o)
    unsigned short* Qb  = (unsigned short*)ws; ws += (size_t)B_ * H_ * N_ * HD_ * 2; // 8.4 MB
    unsigned short* Kb  = (unsigned short*)ws; ws += (size_t)B_ * H_ * N_ * HD_ * 2;
    unsigned short* Vs  = (unsigned short*)ws; ws += (size_t)B_ * H_ * N_ * HD_ * 2;
    unsigned short* att = (unsigned short*)ws; ws += (size_t)16384 * 256 * 2;
    unsigned int*   mbg = (unsigned int*)ws;   ws += (size_t)B_ * N_ * 64 * 4;  // 4.2 MB

    k_prep_x<<<4096, 256, 0, stream>>>(x, xbf, 1048576);
    k_prep_w<<<dim3(256, 4), 256, 0, stream>>>(Wq, Wk, Wv, Wo, wt);
    k_mask<<<2048, 256, 0, stream>>>(adj, mbg);
    k_qkv<<<dim3(256, 3), 256, 0, stream>>>(xbf, wt, bq, bk, bv, Qb, Kb, Vs);
    k_attn<<<512, 512, 0, stream>>>(Qb, Kb, Vs, mbg, att);
    k_outln<<<256, 256, 0, stream>>>(att, wt + 3 * 65536, bo, x, gamma, beta, out);
}

// Round 6
// 186.623 us; speedup vs baseline: 1.0245x; 1.0245x over previous
//
#include <hip/hip_runtime.h>
#include <hip/hip_bf16.h>
#include <cstdint>
#include <cstddef>

// Problem constants
#define B_ 8
#define N_ 2048
#define D_ 256
#define H_ 8
#define HD_ 32
#define LN_EPS 1e-5f
#define QSCALE 0.25506275f  // log2(e)/sqrt(32): folded into Q so p = exp2(q'.k)

typedef __attribute__((ext_vector_type(8))) short short8;
typedef __attribute__((ext_vector_type(4))) float f32x4;
typedef __attribute__((ext_vector_type(16))) float f32x16;

static __device__ __forceinline__ float exp2v(float x) {
#if __has_builtin(__builtin_amdgcn_exp2f)
    return __builtin_amdgcn_exp2f(x);
#else
    float r;
    asm("v_exp_f32 %0, %1" : "=v"(r) : "v"(x));
    return r;
#endif
}

static __device__ __forceinline__ unsigned short f2bf(float f) {
    union { float f; unsigned int u; } v; v.f = f;
    unsigned int r = v.u + 0x7fffu + ((v.u >> 16) & 1u);
    return (unsigned short)(r >> 16);
}

static __device__ __forceinline__ unsigned int cvtpk(float lo, float hi) {
    unsigned int d;
    asm("v_cvt_pk_bf16_f32 %0, %1, %2" : "=v"(d) : "v"(lo), "v"(hi));
    return d;
}

// ---------------- prep: x fp32 -> bf16 ----------------
__global__ __launch_bounds__(256) void k_prep_x(const float* __restrict__ x,
                                                unsigned short* __restrict__ xbf, int n4) {
    int i = blockIdx.x * 256 + threadIdx.x;
    if (i >= n4) return;
    float4 v = reinterpret_cast<const float4*>(x)[i];
    ushort4 o;
    o.x = f2bf(v.x); o.y = f2bf(v.y); o.z = f2bf(v.z); o.w = f2bf(v.w);
    reinterpret_cast<ushort4*>(xbf)[i] = o;
}

// ---------------- prep: W fp32 -> bf16 transposed wt[mat][col][k] ----------------
__global__ __launch_bounds__(256) void k_prep_w(const float* __restrict__ w0, const float* __restrict__ w1,
                                                const float* __restrict__ w2, const float* __restrict__ w3,
                                                unsigned short* __restrict__ wt) {
    int c = blockIdx.x, mat = blockIdx.y, k = threadIdx.x;
    const float* w = (mat == 0) ? w0 : (mat == 1) ? w1 : (mat == 2) ? w2 : w3;
    wt[((size_t)(mat * 256 + c)) * 256 + k] = f2bf(w[k * 256 + c]);
}

// ---------------- adjacency -> bitmask (streaming) ----------------
// Phase-split to force memory-level parallelism: 16 independent int4 loads
// issued back-to-back into v[16] (no consumer between them), THEN the
// nibble/shfl-OR pack. 16 KB in flight per wave covers HBM latency.
__global__ __launch_bounds__(256) void k_mask(const int* __restrict__ adj,
                                              unsigned int* __restrict__ mbg) {
    int wave = (blockIdx.x * 256 + threadIdx.x) >> 6;   // 0..8191
    int lane = threadIdx.x & 63;
    int shamt = 4 * (lane & 7);
    int g8 = lane >> 3;
    const int4* p = reinterpret_cast<const int4*>(adj) + (size_t)wave * 1024 + lane;
    unsigned int* outp = mbg + (size_t)wave * 128;

    int4 v[16];
#pragma unroll
    for (int i = 0; i < 16; ++i)
        v[i] = p[i * 64];

#pragma unroll
    for (int i = 0; i < 16; ++i) {
        unsigned int nib = (v[i].x != 0 ? 1u : 0u) | (v[i].y != 0 ? 2u : 0u)
                         | (v[i].z != 0 ? 4u : 0u) | (v[i].w != 0 ? 8u : 0u);
        unsigned int r = nib << shamt;
        r |= (unsigned int)__shfl_xor((int)r, 1, 64);
        r |= (unsigned int)__shfl_xor((int)r, 2, 64);
        r |= (unsigned int)__shfl_xor((int)r, 4, 64);
        if ((lane & 7) == 0) outp[i * 8 + g8] = r;
    }
}

// ---------------- fused QKV projection GEMM ----------------
__global__ __launch_bounds__(256) void k_qkv(const unsigned short* __restrict__ xbf,
                                             const unsigned short* __restrict__ wt,
                                             const float* __restrict__ bq, const float* __restrict__ bk,
                                             const float* __restrict__ bv,
                                             unsigned short* __restrict__ Qb, unsigned short* __restrict__ Kb,
                                             unsigned short* __restrict__ Vs) {
    int mat = blockIdx.y;
    int lane = threadIdx.x & 63;
    int wv = threadIdx.x >> 6;
    int row0 = blockIdx.x * 64 + wv * 16;
    int l15 = lane & 15, lg = lane >> 4;
    const float* bias = (mat == 0) ? bq : (mat == 1) ? bk : bv;
    const float qs = (mat == 0) ? QSCALE : 1.0f;
    const unsigned short* wm = wt + (size_t)mat * 65536;

    short8 af[8];
    const unsigned short* xrow = xbf + (size_t)(row0 + l15) * 256 + lg * 8;
#pragma unroll
    for (int kk = 0; kk < 8; ++kk)
        af[kk] = *reinterpret_cast<const short8*>(xrow + kk * 32);

    int b = row0 >> 11;            // 2048 rows per batch; 64-row blocks never cross
    int nbase = (row0 & 2047) + lg * 4;

    for (int ci = 0; ci < 16; ++ci) {
        const unsigned short* wrow = wm + (size_t)(ci * 16 + l15) * 256 + lg * 8;
        f32x4 acc = {0.f, 0.f, 0.f, 0.f};
#pragma unroll
        for (int kk = 0; kk < 8; ++kk) {
            short8 bfg = *reinterpret_cast<const short8*>(wrow + kk * 32);
            acc = __builtin_amdgcn_mfma_f32_16x16x32_bf16(af[kk], bfg, acc, 0, 0, 0);
        }
        int col = ci * 16 + l15;
        float bcol = bias[col];
        int h = col >> 5, hd = col & 31;
        if (mat < 2) {
            unsigned short* dst = (mat == 0) ? Qb : Kb;
#pragma unroll
            for (int r = 0; r < 4; ++r) {
                size_t off = ((size_t)(b * 8 + h) * 2048 + nbase + r) * 32 + hd;
                dst[off] = f2bf((acc[r] + bcol) * qs);
            }
        } else {
            // V fragment-tile layout
            size_t off = (size_t)(b * 8 + h) * 65536
                       + ((size_t)(nbase >> 4) * 32 + hd) * 16 + (nbase & 15);
            ushort4 o;
            o.x = f2bf(acc[0] + bcol); o.y = f2bf(acc[1] + bcol);
            o.z = f2bf(acc[2] + bcol); o.w = f2bf(acc[3] + bcol);
            *reinterpret_cast<ushort4*>(Vs + off) = o;
        }
    }
}

// ---------------- masked attention ----------------
// 1-D grid of 512: b = blk&7 (XCD-affine), q0 = (blk>>3)*32. 8 waves, wave = head.
// S^T = mfma(K, Q); p = bit ? exp2(s) : 0; P packed via cvt_pk + permlane32_swap;
// att^T += mfma(V_tile, P). Softmax denominator via ones-MFMA: onesacc = mfma(1, P)
// puts sum_k P[k][q] in every acc reg (col q = lane&31) -> no VALU adds, no shfl.
__global__ __launch_bounds__(512, 4) void k_attn(const unsigned short* __restrict__ Qb,
                                                 const unsigned short* __restrict__ Kb,
                                                 const unsigned short* __restrict__ Vs,
                                                 const unsigned int* __restrict__ mbg,
                                                 unsigned short* __restrict__ att) {
    __shared__ unsigned int mbits[32][66];   // +2 pad: 2-way max conflict (free)
    int tid = threadIdx.x;
    int lane = tid & 63, hw = tid >> 6;
    int l31 = lane & 31, hi = lane >> 5;
    int b = blockIdx.x & 7;
    int q0 = (blockIdx.x >> 3) * 32;

    // ---- load this block's 8KB bitmask (one int4 per thread) ----
    {
        int row = tid >> 4, c0 = (tid & 15) * 4;
        uint4 v4 = *reinterpret_cast<const uint4*>(mbg + ((size_t)(b * N_ + q0 + row)) * 64 + c0);
        mbits[row][c0] = v4.x; mbits[row][c0 + 1] = v4.y;
        mbits[row][c0 + 2] = v4.z; mbits[row][c0 + 3] = v4.w;
    }
    __syncthreads();

    int bh = b * 8 + hw;
    const unsigned short* Qh = Qb + (size_t)bh * N_ * HD_;
    const unsigned short* Kh = Kb + (size_t)bh * N_ * HD_;
    const unsigned short* Vh = Vs + (size_t)bh * 65536;

    short8 qf0 = *reinterpret_cast<const short8*>(Qh + (size_t)(q0 + l31) * HD_ + hi * 8);
    short8 qf1 = *reinterpret_cast<const short8*>(Qh + (size_t)(q0 + l31) * HD_ + hi * 8 + 16);
    const unsigned short* krow = Kh + (size_t)l31 * HD_ + hi * 8;
    const unsigned short* vfp = Vh + (size_t)l31 * 16 + hi * 8;   // + tile*512

    const f32x16 fz = {0.f,0.f,0.f,0.f,0.f,0.f,0.f,0.f,0.f,0.f,0.f,0.f,0.f,0.f,0.f,0.f};
    const short8 onesf = {0x3F80, 0x3F80, 0x3F80, 0x3F80, 0x3F80, 0x3F80, 0x3F80, 0x3F80};
    f32x16 attacc = fz;
    f32x16 onesacc = fz;
    const unsigned int* mrow = &mbits[l31][0];

#pragma unroll 2
    for (int m0 = 0; m0 < N_; m0 += 32) {
        short8 kf0 = *reinterpret_cast<const short8*>(krow + (size_t)m0 * HD_);
        short8 kf1 = *reinterpret_cast<const short8*>(krow + (size_t)m0 * HD_ + 16);
        short8 vf0 = *reinterpret_cast<const short8*>(vfp + (size_t)(m0 >> 4) * 512);
        short8 vf1 = *reinterpret_cast<const short8*>(vfp + (size_t)(m0 >> 4) * 512 + 512);
        unsigned int wl = mrow[m0 >> 5] >> (4 * hi);   // lane's bits now at 8g..8g+3

        __builtin_amdgcn_s_setprio(1);
        f32x16 s = __builtin_amdgcn_mfma_f32_32x32x16_bf16(kf0, qf0, fz, 0, 0, 0);
        s = __builtin_amdgcn_mfma_f32_32x32x16_bf16(kf1, qf1, s, 0, 0, 0);
        __builtin_amdgcn_s_setprio(0);

        unsigned int pd[4][2];
#pragma unroll
        for (int g = 0; g < 4; ++g) {
            unsigned int nib = (wl >> (8 * g)) & 15u;
            float p0 = (nib & 1u) ? exp2v(s[4 * g + 0]) : 0.f;
            float p1 = (nib & 2u) ? exp2v(s[4 * g + 1]) : 0.f;
            float p2 = (nib & 4u) ? exp2v(s[4 * g + 2]) : 0.f;
            float p3 = (nib & 8u) ? exp2v(s[4 * g + 3]) : 0.f;
            pd[g][0] = cvtpk(p0, p1);
            pd[g][1] = cvtpk(p2, p3);
        }
        asm("v_permlane32_swap_b32 %0, %1" : "+v"(pd[0][0]), "+v"(pd[1][0]));
        asm("v_permlane32_swap_b32 %0, %1" : "+v"(pd[0][1]), "+v"(pd[1][1]));
        asm("v_permlane32_swap_b32 %0, %1" : "+v"(pd[2][0]), "+v"(pd[3][0]));
        asm("v_permlane32_swap_b32 %0, %1" : "+v"(pd[2][1]), "+v"(pd[3][1]));

        union { short8 s8; unsigned int u[4]; } bf0, bf1;
        bf0.u[0] = pd[0][0]; bf0.u[1] = pd[0][1]; bf0.u[2] = pd[1][0]; bf0.u[3] = pd[1][1];
        bf1.u[0] = pd[2][0]; bf1.u[1] = pd[2][1]; bf1.u[2] = pd[3][0]; bf1.u[3] = pd[3][1];

        __builtin_amdgcn_s_setprio(1);
        attacc = __builtin_amdgcn_mfma_f32_32x32x16_bf16(vf0, bf0.s8, attacc, 0, 0, 0);
        attacc = __builtin_amdgcn_mfma_f32_32x32x16_bf16(vf1, bf1.s8, attacc, 0, 0, 0);
        onesacc = __builtin_amdgcn_mfma_f32_32x32x16_bf16(onesf, bf0.s8, onesacc, 0, 0, 0);
        onesacc = __builtin_amdgcn_mfma_f32_32x32x16_bf16(onesf, bf1.s8, onesacc, 0, 0, 0);
        __builtin_amdgcn_s_setprio(0);
    }

    float rcp = 1.f / onesacc[0];   // every reg holds sum_k P[k][q=l31]

    unsigned short* arow = att + ((size_t)b * N_ + q0 + l31) * D_ + hw * HD_;
#pragma unroll
    for (int g = 0; g < 4; ++g) {
        ushort4 o;
        o.x = f2bf(attacc[4 * g + 0] * rcp);
        o.y = f2bf(attacc[4 * g + 1] * rcp);
        o.z = f2bf(attacc[4 * g + 2] * rcp);
        o.w = f2bf(attacc[4 * g + 3] * rcp);
        *reinterpret_cast<ushort4*>(arow + 8 * g + 4 * hi) = o;
    }
}

// ---------------- out projection + residual + LayerNorm ----------------
__global__ __launch_bounds__(256) void k_outln(const unsigned short* __restrict__ att,
                                               const unsigned short* __restrict__ wot,
                                               const float* __restrict__ bo, const float* __restrict__ x,
                                               const float* __restrict__ gamma, const float* __restrict__ beta,
                                               float* __restrict__ out) {
    int lane = threadIdx.x & 63, wv = threadIdx.x >> 6;
    int l15 = lane & 15, lg = lane >> 4;
    int row0 = blockIdx.x * 64 + wv * 16;

    short8 af[8];
    const unsigned short* arow = att + (size_t)(row0 + l15) * 256 + lg * 8;
#pragma unroll
    for (int kk = 0; kk < 8; ++kk)
        af[kk] = *reinterpret_cast<const short8*>(arow + kk * 32);

    float v[16][4];
#pragma unroll
    for (int ci = 0; ci < 16; ++ci) {
        const unsigned short* wrow = wot + (size_t)(ci * 16 + l15) * 256 + lg * 8;
        f32x4 acc = {0.f, 0.f, 0.f, 0.f};
#pragma unroll
        for (int kk = 0; kk < 8; ++kk) {
            short8 bfg = *reinterpret_cast<const short8*>(wrow + kk * 32);
            acc = __builtin_amdgcn_mfma_f32_16x16x32_bf16(af[kk], bfg, acc, 0, 0, 0);
        }
        float bcol = bo[ci * 16 + l15];
#pragma unroll
        for (int r = 0; r < 4; ++r)
            v[ci][r] = acc[r] + bcol + x[(size_t)(row0 + lg * 4 + r) * 256 + ci * 16 + l15];
    }

    float sum[4] = {0.f, 0.f, 0.f, 0.f}, sq[4] = {0.f, 0.f, 0.f, 0.f};
#pragma unroll
    for (int ci = 0; ci < 16; ++ci)
#pragma unroll
        for (int r = 0; r < 4; ++r) {
            sum[r] += v[ci][r];
            sq[r] += v[ci][r] * v[ci][r];
        }
#pragma unroll
    for (int d = 1; d < 16; d <<= 1)
#pragma unroll
        for (int r = 0; r < 4; ++r) {
            sum[r] += __shfl_xor(sum[r], d, 64);
            sq[r] += __shfl_xor(sq[r], d, 64);
        }

    float mu[4], rs[4];
#pragma unroll
    for (int r = 0; r < 4; ++r) {
        mu[r] = sum[r] * (1.f / 256.f);
        float var = sq[r] * (1.f / 256.f) - mu[r] * mu[r];
        rs[r] = rsqrtf(var + LN_EPS);
    }

#pragma unroll
    for (int ci = 0; ci < 16; ++ci) {
        float g = gamma[ci * 16 + l15], be = beta[ci * 16 + l15];
#pragma unroll
        for (int r = 0; r < 4; ++r)
            out[(size_t)(row0 + lg * 4 + r) * 256 + ci * 16 + l15] = (v[ci][r] - mu[r]) * rs[r] * g + be;
    }
}

extern "C" void kernel_launch(void* const* d_in, const int* in_sizes, int n_in,
                              void* d_out, int out_size, void* d_ws, size_t ws_size,
                              hipStream_t stream) {
    (void)in_sizes; (void)n_in; (void)out_size; (void)ws_size;
    const float* x     = (const float*)d_in[0];
    const int*   adj   = (const int*)d_in[1];
    const float* Wq    = (const float*)d_in[2];
    const float* bq    = (const float*)d_in[3];
    const float* Wk    = (const float*)d_in[4];
    const float* bk    = (const float*)d_in[5];
    const float* Wv    = (const float*)d_in[6];
    const float* bv    = (const float*)d_in[7];
    const float* Wo    = (const float*)d_in[8];
    const float* bo    = (const float*)d_in[9];
    const float* gamma = (const float*)d_in[10];
    const float* beta  = (const float*)d_in[11];
    float* out = (float*)d_out;

    char* ws = (char*)d_ws;
    unsigned short* xbf = (unsigned short*)ws; ws += (size_t)16384 * 256 * 2;   // 8.4 MB
    unsigned short* wt  = (unsigned short*)ws; ws += (size_t)4 * 256 * 256 * 2; // 0.5 MB (q,k,v,o)
    unsigned short* Qb  = (unsigned short*)ws; ws += (size_t)B_ * H_ * N_ * HD_ * 2; // 8.4 MB
    unsigned short* Kb  = (unsigned short*)ws; ws += (size_t)B_ * H_ * N_ * HD_ * 2;
    unsigned short* Vs  = (unsigned short*)ws; ws += (size_t)B_ * H_ * N_ * HD_ * 2;
    unsigned short* att = (unsigned short*)ws; ws += (size_t)16384 * 256 * 2;
    unsigned int*   mbg = (unsigned int*)ws;   ws += (size_t)B_ * N_ * 64 * 4;  // 4.2 MB

    k_prep_x<<<4096, 256, 0, stream>>>(x, xbf, 1048576);
    k_prep_w<<<dim3(256, 4), 256, 0, stream>>>(Wq, Wk, Wv, Wo, wt);
    k_mask<<<2048, 256, 0, stream>>>(adj, mbg);
    k_qkv<<<dim3(256, 3), 256, 0, stream>>>(xbf, wt, bq, bk, bv, Qb, Kb, Vs);
    k_attn<<<512, 512, 0, stream>>>(Qb, Kb, Vs, mbg, att);
    k_outln<<<256, 256, 0, stream>>>(att, wt + 3 * 65536, bo, x, gamma, beta, out);
}

// Round 7
// 184.120 us; speedup vs baseline: 1.0384x; 1.0136x over previous
//
#include <hip/hip_runtime.h>
#include <hip/hip_bf16.h>
#include <cstdint>
#include <cstddef>

// Problem constants
#define B_ 8
#define N_ 2048
#define D_ 256
#define H_ 8
#define HD_ 32
#define LN_EPS 1e-5f
#define QSCALE 0.25506275f  // log2(e)/sqrt(32): folded into Q so p = exp2(q'.k)

typedef __attribute__((ext_vector_type(8))) short short8;
typedef __attribute__((ext_vector_type(4))) float f32x4;
typedef __attribute__((ext_vector_type(16))) float f32x16;

static __device__ __forceinline__ float exp2v(float x) {
#if __has_builtin(__builtin_amdgcn_exp2f)
    return __builtin_amdgcn_exp2f(x);
#else
    float r;
    asm("v_exp_f32 %0, %1" : "=v"(r) : "v"(x));
    return r;
#endif
}

static __device__ __forceinline__ unsigned short f2bf(float f) {
    union { float f; unsigned int u; } v; v.f = f;
    unsigned int r = v.u + 0x7fffu + ((v.u >> 16) & 1u);
    return (unsigned short)(r >> 16);
}

static __device__ __forceinline__ float bf2f(unsigned short u) {
    union { unsigned int u; float f; } v; v.u = ((unsigned int)u) << 16;
    return v.f;
}

static __device__ __forceinline__ unsigned int cvtpk(float lo, float hi) {
    unsigned int d;
    asm("v_cvt_pk_bf16_f32 %0, %1, %2" : "=v"(d) : "v"(lo), "v"(hi));
    return d;
}

// ---------------- prep: x fp32 -> bf16 ----------------
__global__ __launch_bounds__(256) void k_prep_x(const float* __restrict__ x,
                                                unsigned short* __restrict__ xbf, int n4) {
    int i = blockIdx.x * 256 + threadIdx.x;
    if (i >= n4) return;
    float4 v = reinterpret_cast<const float4*>(x)[i];
    ushort4 o;
    o.x = f2bf(v.x); o.y = f2bf(v.y); o.z = f2bf(v.z); o.w = f2bf(v.w);
    reinterpret_cast<ushort4*>(xbf)[i] = o;
}

// ---------------- prep: W fp32 -> bf16 transposed wt[mat][col][k] ----------------
__global__ __launch_bounds__(256) void k_prep_w(const float* __restrict__ w0, const float* __restrict__ w1,
                                                const float* __restrict__ w2, const float* __restrict__ w3,
                                                unsigned short* __restrict__ wt) {
    int c = blockIdx.x, mat = blockIdx.y, k = threadIdx.x;
    const float* w = (mat == 0) ? w0 : (mat == 1) ? w1 : (mat == 2) ? w2 : w3;
    wt[((size_t)(mat * 256 + c)) * 256 + k] = f2bf(w[k * 256 + c]);
}

// ---------------- adjacency -> bitmask (streaming) ----------------
// Phase-split to force memory-level parallelism: 16 independent int4 loads
// issued back-to-back into v[16], THEN the nibble/shfl-OR pack.
__global__ __launch_bounds__(256) void k_mask(const int* __restrict__ adj,
                                              unsigned int* __restrict__ mbg) {
    int wave = (blockIdx.x * 256 + threadIdx.x) >> 6;   // 0..8191
    int lane = threadIdx.x & 63;
    int shamt = 4 * (lane & 7);
    int g8 = lane >> 3;
    const int4* p = reinterpret_cast<const int4*>(adj) + (size_t)wave * 1024 + lane;
    unsigned int* outp = mbg + (size_t)wave * 128;

    int4 v[16];
#pragma unroll
    for (int i = 0; i < 16; ++i)
        v[i] = p[i * 64];

#pragma unroll
    for (int i = 0; i < 16; ++i) {
        unsigned int nib = (v[i].x != 0 ? 1u : 0u) | (v[i].y != 0 ? 2u : 0u)
                         | (v[i].z != 0 ? 4u : 0u) | (v[i].w != 0 ? 8u : 0u);
        unsigned int r = nib << shamt;
        r |= (unsigned int)__shfl_xor((int)r, 1, 64);
        r |= (unsigned int)__shfl_xor((int)r, 2, 64);
        r |= (unsigned int)__shfl_xor((int)r, 4, 64);
        if ((lane & 7) == 0) outp[i * 8 + g8] = r;
    }
}

// ---------------- fused QKV projection GEMM ----------------
__global__ __launch_bounds__(256) void k_qkv(const unsigned short* __restrict__ xbf,
                                             const unsigned short* __restrict__ wt,
                                             const float* __restrict__ bq, const float* __restrict__ bk,
                                             const float* __restrict__ bv,
                                             unsigned short* __restrict__ Qb, unsigned short* __restrict__ Kb,
                                             unsigned short* __restrict__ Vs) {
    int mat = blockIdx.y;
    int lane = threadIdx.x & 63;
    int wv = threadIdx.x >> 6;
    int row0 = blockIdx.x * 64 + wv * 16;
    int l15 = lane & 15, lg = lane >> 4;
    const float* bias = (mat == 0) ? bq : (mat == 1) ? bk : bv;
    const float qs = (mat == 0) ? QSCALE : 1.0f;
    const unsigned short* wm = wt + (size_t)mat * 65536;

    short8 af[8];
    const unsigned short* xrow = xbf + (size_t)(row0 + l15) * 256 + lg * 8;
#pragma unroll
    for (int kk = 0; kk < 8; ++kk)
        af[kk] = *reinterpret_cast<const short8*>(xrow + kk * 32);

    int b = row0 >> 11;            // 2048 rows per batch; 64-row blocks never cross
    int nbase = (row0 & 2047) + lg * 4;

    for (int ci = 0; ci < 16; ++ci) {
        const unsigned short* wrow = wm + (size_t)(ci * 16 + l15) * 256 + lg * 8;
        f32x4 acc = {0.f, 0.f, 0.f, 0.f};
#pragma unroll
        for (int kk = 0; kk < 8; ++kk) {
            short8 bfg = *reinterpret_cast<const short8*>(wrow + kk * 32);
            acc = __builtin_amdgcn_mfma_f32_16x16x32_bf16(af[kk], bfg, acc, 0, 0, 0);
        }
        int col = ci * 16 + l15;
        float bcol = bias[col];
        int h = col >> 5, hd = col & 31;
        if (mat < 2) {
            unsigned short* dst = (mat == 0) ? Qb : Kb;
#pragma unroll
            for (int r = 0; r < 4; ++r) {
                size_t off = ((size_t)(b * 8 + h) * 2048 + nbase + r) * 32 + hd;
                dst[off] = f2bf((acc[r] + bcol) * qs);
            }
        } else {
            // V fragment-tile layout
            size_t off = (size_t)(b * 8 + h) * 65536
                       + ((size_t)(nbase >> 4) * 32 + hd) * 16 + (nbase & 15);
            ushort4 o;
            o.x = f2bf(acc[0] + bcol); o.y = f2bf(acc[1] + bcol);
            o.z = f2bf(acc[2] + bcol); o.w = f2bf(acc[3] + bcol);
            *reinterpret_cast<ushort4*>(Vs + off) = o;
        }
    }
}

// ---------------- masked attention ----------------
// 256-thread blocks (4 waves = 4 heads) for wave-granular occupancy:
// ~92 regs/wave -> 5-6 waves/SIMD vs 4 with 512-thr blocks (block quantization).
// blk: b = blk&7 (XCD-affine), hg = (blk>>3)&1 (head group), q0 = (blk>>4)*32.
// S^T = mfma(K, Q); p = bit ? exp2(s) : 0; P packed via cvt_pk + permlane32_swap;
// att^T += mfma(V_tile, P); denominator via ones-MFMA (no VALU adds, no shfl).
__global__ __launch_bounds__(256, 6) void k_attn(const unsigned short* __restrict__ Qb,
                                                 const unsigned short* __restrict__ Kb,
                                                 const unsigned short* __restrict__ Vs,
                                                 const unsigned int* __restrict__ mbg,
                                                 unsigned short* __restrict__ att) {
    __shared__ unsigned int mbits[32][66];   // +2 pad: 2-way max conflict (free)
    int tid = threadIdx.x;
    int lane = tid & 63;
    int l31 = lane & 31, hi = lane >> 5;
    int b = blockIdx.x & 7;
    int hg = (blockIdx.x >> 3) & 1;
    int q0 = (blockIdx.x >> 4) * 32;
    int head = hg * 4 + (tid >> 6);

    // ---- load this block's 8KB bitmask (two uint4 per thread) ----
    {
        int row = tid >> 3, c0 = (tid & 7) * 8;
        const unsigned int* src = mbg + ((size_t)(b * N_ + q0 + row)) * 64 + c0;
        uint4 v4 = *reinterpret_cast<const uint4*>(src);
        uint4 w4 = *reinterpret_cast<const uint4*>(src + 4);
        mbits[row][c0 + 0] = v4.x; mbits[row][c0 + 1] = v4.y;
        mbits[row][c0 + 2] = v4.z; mbits[row][c0 + 3] = v4.w;
        mbits[row][c0 + 4] = w4.x; mbits[row][c0 + 5] = w4.y;
        mbits[row][c0 + 6] = w4.z; mbits[row][c0 + 7] = w4.w;
    }
    __syncthreads();

    int bh = b * 8 + head;
    const unsigned short* Qh = Qb + (size_t)bh * N_ * HD_;
    const unsigned short* Kh = Kb + (size_t)bh * N_ * HD_;
    const unsigned short* Vh = Vs + (size_t)bh * 65536;

    short8 qf0 = *reinterpret_cast<const short8*>(Qh + (size_t)(q0 + l31) * HD_ + hi * 8);
    short8 qf1 = *reinterpret_cast<const short8*>(Qh + (size_t)(q0 + l31) * HD_ + hi * 8 + 16);
    const unsigned short* krow = Kh + (size_t)l31 * HD_ + hi * 8;
    const unsigned short* vfp = Vh + (size_t)l31 * 16 + hi * 8;   // + tile*512

    const f32x16 fz = {0.f,0.f,0.f,0.f,0.f,0.f,0.f,0.f,0.f,0.f,0.f,0.f,0.f,0.f,0.f,0.f};
    const short8 onesf = {0x3F80, 0x3F80, 0x3F80, 0x3F80, 0x3F80, 0x3F80, 0x3F80, 0x3F80};
    f32x16 attacc = fz;
    f32x16 onesacc = fz;
    const unsigned int* mrow = &mbits[l31][0];

#pragma unroll 2
    for (int m0 = 0; m0 < N_; m0 += 32) {
        short8 kf0 = *reinterpret_cast<const short8*>(krow + (size_t)m0 * HD_);
        short8 kf1 = *reinterpret_cast<const short8*>(krow + (size_t)m0 * HD_ + 16);
        short8 vf0 = *reinterpret_cast<const short8*>(vfp + (size_t)(m0 >> 4) * 512);
        short8 vf1 = *reinterpret_cast<const short8*>(vfp + (size_t)(m0 >> 4) * 512 + 512);
        unsigned int wl = mrow[m0 >> 5] >> (4 * hi);   // lane's bits now at 8g..8g+3

        __builtin_amdgcn_s_setprio(1);
        f32x16 s = __builtin_amdgcn_mfma_f32_32x32x16_bf16(kf0, qf0, fz, 0, 0, 0);
        s = __builtin_amdgcn_mfma_f32_32x32x16_bf16(kf1, qf1, s, 0, 0, 0);
        __builtin_amdgcn_s_setprio(0);

        unsigned int pd[4][2];
#pragma unroll
        for (int g = 0; g < 4; ++g) {
            unsigned int nib = (wl >> (8 * g)) & 15u;
            float p0 = (nib & 1u) ? exp2v(s[4 * g + 0]) : 0.f;
            float p1 = (nib & 2u) ? exp2v(s[4 * g + 1]) : 0.f;
            float p2 = (nib & 4u) ? exp2v(s[4 * g + 2]) : 0.f;
            float p3 = (nib & 8u) ? exp2v(s[4 * g + 3]) : 0.f;
            pd[g][0] = cvtpk(p0, p1);
            pd[g][1] = cvtpk(p2, p3);
        }
        asm("v_permlane32_swap_b32 %0, %1" : "+v"(pd[0][0]), "+v"(pd[1][0]));
        asm("v_permlane32_swap_b32 %0, %1" : "+v"(pd[0][1]), "+v"(pd[1][1]));
        asm("v_permlane32_swap_b32 %0, %1" : "+v"(pd[2][0]), "+v"(pd[3][0]));
        asm("v_permlane32_swap_b32 %0, %1" : "+v"(pd[2][1]), "+v"(pd[3][1]));

        union { short8 s8; unsigned int u[4]; } bf0, bf1;
        bf0.u[0] = pd[0][0]; bf0.u[1] = pd[0][1]; bf0.u[2] = pd[1][0]; bf0.u[3] = pd[1][1];
        bf1.u[0] = pd[2][0]; bf1.u[1] = pd[2][1]; bf1.u[2] = pd[3][0]; bf1.u[3] = pd[3][1];

        __builtin_amdgcn_s_setprio(1);
        attacc = __builtin_amdgcn_mfma_f32_32x32x16_bf16(vf0, bf0.s8, attacc, 0, 0, 0);
        attacc = __builtin_amdgcn_mfma_f32_32x32x16_bf16(vf1, bf1.s8, attacc, 0, 0, 0);
        onesacc = __builtin_amdgcn_mfma_f32_32x32x16_bf16(onesf, bf0.s8, onesacc, 0, 0, 0);
        onesacc = __builtin_amdgcn_mfma_f32_32x32x16_bf16(onesf, bf1.s8, onesacc, 0, 0, 0);
        __builtin_amdgcn_s_setprio(0);
    }

    float rcp = 1.f / onesacc[0];   // every reg holds sum_k P[k][q=l31]

    unsigned short* arow = att + ((size_t)b * N_ + q0 + l31) * D_ + head * HD_;
#pragma unroll
    for (int g = 0; g < 4; ++g) {
        ushort4 o;
        o.x = f2bf(attacc[4 * g + 0] * rcp);
        o.y = f2bf(attacc[4 * g + 1] * rcp);
        o.z = f2bf(attacc[4 * g + 2] * rcp);
        o.w = f2bf(attacc[4 * g + 3] * rcp);
        *reinterpret_cast<ushort4*>(arow + 8 * g + 4 * hi) = o;
    }
}

// ---------------- out projection + residual + LayerNorm ----------------
// Residual read from xbf (bf16) instead of fp32 x: -33MB HBM.
__global__ __launch_bounds__(256) void k_outln(const unsigned short* __restrict__ att,
                                               const unsigned short* __restrict__ wot,
                                               const float* __restrict__ bo,
                                               const unsigned short* __restrict__ xbf,
                                               const float* __restrict__ gamma, const float* __restrict__ beta,
                                               float* __restrict__ out) {
    int lane = threadIdx.x & 63, wv = threadIdx.x >> 6;
    int l15 = lane & 15, lg = lane >> 4;
    int row0 = blockIdx.x * 64 + wv * 16;

    short8 af[8];
    const unsigned short* arow = att + (size_t)(row0 + l15) * 256 + lg * 8;
#pragma unroll
    for (int kk = 0; kk < 8; ++kk)
        af[kk] = *reinterpret_cast<const short8*>(arow + kk * 32);

    float v[16][4];
#pragma unroll
    for (int ci = 0; ci < 16; ++ci) {
        const unsigned short* wrow = wot + (size_t)(ci * 16 + l15) * 256 + lg * 8;
        f32x4 acc = {0.f, 0.f, 0.f, 0.f};
#pragma unroll
        for (int kk = 0; kk < 8; ++kk) {
            short8 bfg = *reinterpret_cast<const short8*>(wrow + kk * 32);
            acc = __builtin_amdgcn_mfma_f32_16x16x32_bf16(af[kk], bfg, acc, 0, 0, 0);
        }
        float bcol = bo[ci * 16 + l15];
#pragma unroll
        for (int r = 0; r < 4; ++r)
            v[ci][r] = acc[r] + bcol + bf2f(xbf[(size_t)(row0 + lg * 4 + r) * 256 + ci * 16 + l15]);
    }

    float sum[4] = {0.f, 0.f, 0.f, 0.f}, sq[4] = {0.f, 0.f, 0.f, 0.f};
#pragma unroll
    for (int ci = 0; ci < 16; ++ci)
#pragma unroll
        for (int r = 0; r < 4; ++r) {
            sum[r] += v[ci][r];
            sq[r] += v[ci][r] * v[ci][r];
        }
#pragma unroll
    for (int d = 1; d < 16; d <<= 1)
#pragma unroll
        for (int r = 0; r < 4; ++r) {
            sum[r] += __shfl_xor(sum[r], d, 64);
            sq[r] += __shfl_xor(sq[r], d, 64);
        }

    float mu[4], rs[4];
#pragma unroll
    for (int r = 0; r < 4; ++r) {
        mu[r] = sum[r] * (1.f / 256.f);
        float var = sq[r] * (1.f / 256.f) - mu[r] * mu[r];
        rs[r] = rsqrtf(var + LN_EPS);
    }

#pragma unroll
    for (int ci = 0; ci < 16; ++ci) {
        float g = gamma[ci * 16 + l15], be = beta[ci * 16 + l15];
#pragma unroll
        for (int r = 0; r < 4; ++r)
            out[(size_t)(row0 + lg * 4 + r) * 256 + ci * 16 + l15] = (v[ci][r] - mu[r]) * rs[r] * g + be;
    }
}

extern "C" void kernel_launch(void* const* d_in, const int* in_sizes, int n_in,
                              void* d_out, int out_size, void* d_ws, size_t ws_size,
                              hipStream_t stream) {
    (void)in_sizes; (void)n_in; (void)out_size; (void)ws_size;
    const float* x     = (const float*)d_in[0];
    const int*   adj   = (const int*)d_in[1];
    const float* Wq    = (const float*)d_in[2];
    const float* bq    = (const float*)d_in[3];
    const float* Wk    = (const float*)d_in[4];
    const float* bk    = (const float*)d_in[5];
    const float* Wv    = (const float*)d_in[6];
    const float* bv    = (const float*)d_in[7];
    const float* Wo    = (const float*)d_in[8];
    const float* bo    = (const float*)d_in[9];
    const float* gamma = (const float*)d_in[10];
    const float* beta  = (const float*)d_in[11];
    float* out = (float*)d_out;

    char* ws = (char*)d_ws;
    unsigned short* xbf = (unsigned short*)ws; ws += (size_t)16384 * 256 * 2;   // 8.4 MB
    unsigned short* wt  = (unsigned short*)ws; ws += (size_t)4 * 256 * 256 * 2; // 0.5 MB (q,k,v,o)
    unsigned short* Qb  = (unsigned short*)ws; ws += (size_t)B_ * H_ * N_ * HD_ * 2; // 8.4 MB
    unsigned short* Kb  = (unsigned short*)ws; ws += (size_t)B_ * H_ * N_ * HD_ * 2;
    unsigned short* Vs  = (unsigned short*)ws; ws += (size_t)B_ * H_ * N_ * HD_ * 2;
    unsigned short* att = (unsigned short*)ws; ws += (size_t)16384 * 256 * 2;
    unsigned int*   mbg = (unsigned int*)ws;   ws += (size_t)B_ * N_ * 64 * 4;  // 4.2 MB

    k_prep_x<<<4096, 256, 0, stream>>>(x, xbf, 1048576);
    k_prep_w<<<dim3(256, 4), 256, 0, stream>>>(Wq, Wk, Wv, Wo, wt);
    k_mask<<<2048, 256, 0, stream>>>(adj, mbg);
    k_qkv<<<dim3(256, 3), 256, 0, stream>>>(xbf, wt, bq, bk, bv, Qb, Kb, Vs);
    k_attn<<<1024, 256, 0, stream>>>(Qb, Kb, Vs, mbg, att);
    k_outln<<<256, 256, 0, stream>>>(att, wt + 3 * 65536, bo, xbf, gamma, beta, out);
}